// Round 5
// baseline (2868.899 us; speedup 1.0000x reference)
//
#include <hip/hip_runtime.h>

typedef unsigned short u16;
typedef __bf16 bf16x8 __attribute__((ext_vector_type(8)));
typedef float f32x4 __attribute__((ext_vector_type(4)));
typedef unsigned short u16x4 __attribute__((ext_vector_type(4)));

__device__ __forceinline__ u16 f2bf(float f) {
  union { float f; unsigned int u; } v; v.f = f;
  return (u16)((v.u + 0x7FFFu + ((v.u >> 16) & 1u)) >> 16);
}

__device__ __forceinline__ void gload16(const void* g, void* l) {
  __builtin_amdgcn_global_load_lds(
      (const __attribute__((address_space(1))) unsigned int*)g,
      (__attribute__((address_space(3))) unsigned int*)l, 16, 0, 0);
}

// ---------------------------------------------------------------------------
// Weight prep
// ---------------------------------------------------------------------------
__global__ void transpose_cast_kernel(const float* __restrict__ W, u16* __restrict__ WT,
                                      int R, int C) {
  __shared__ float tile[32][33];
  const int tx = threadIdx.x, ty = threadIdx.y;
  const size_t zoff = (size_t)blockIdx.z * R * C;
  const int c0 = blockIdx.x * 32, r0 = blockIdx.y * 32;
#pragma unroll
  for (int k = 0; k < 32; k += 8)
    tile[ty + k][tx] = W[zoff + (size_t)(r0 + ty + k) * C + (c0 + tx)];
  __syncthreads();
#pragma unroll
  for (int k = 0; k < 32; k += 8)
    WT[zoff + (size_t)(c0 + ty + k) * R + (r0 + tx)] = f2bf(tile[tx][ty + k]);
}

// lm_head (50257 x 1024 f32) -> bf16 padded to 50432 rows (pad rows zero)
__global__ void lm_cast_kernel(const float* __restrict__ lm, u16* __restrict__ out) {
  const int row = blockIdx.x;
  const int t = threadIdx.x;
  u16x4 o = {0, 0, 0, 0};
  if (row < 50257) {
    float4 v = *(const float4*)(lm + (size_t)row * 1024 + t * 4);
    o.x = f2bf(v.x); o.y = f2bf(v.y); o.z = f2bf(v.z); o.w = f2bf(v.w);
  }
  *(u16x4*)(out + (size_t)row * 1024 + t * 4) = o;
}

__global__ void embed_kernel(const int* __restrict__ ids, const float* __restrict__ embed,
                             float* __restrict__ x) {
  const int row = blockIdx.x;
  const int id = ids[row];
  const int t = threadIdx.x;
  *(float4*)(x + (size_t)row * 1024 + t * 4) =
      *(const float4*)(embed + (size_t)id * 1024 + t * 4);
}

// ---------------------------------------------------------------------------
// Fused residual + RMSNorm: v = x + P0 + P1 + bias; xout = v; h = rms(v)*w
// P = two contiguous M*D f32 partials (or null). bias/xout optional.
// ---------------------------------------------------------------------------
__global__ void norm_fused(const float* __restrict__ x, const float* __restrict__ P,
                           const float* __restrict__ bias, const float* __restrict__ w,
                           float* __restrict__ xout, u16* __restrict__ h) {
  const int row = blockIdx.x, tid = threadIdx.x;
  const size_t ro = (size_t)row * 1024 + tid * 4;
  float4 v = *(const float4*)(x + ro);
  if (P) {
    float4 a = *(const float4*)(P + ro);
    float4 b = *(const float4*)(P + 4194304 + ro);
    v.x += a.x + b.x; v.y += a.y + b.y; v.z += a.z + b.z; v.w += a.w + b.w;
  }
  if (bias) {
    float4 bb = *(const float4*)(bias + tid * 4);
    v.x += bb.x; v.y += bb.y; v.z += bb.z; v.w += bb.w;
  }
  if (xout) *(float4*)(xout + ro) = v;
  float ss = v.x * v.x + v.y * v.y + v.z * v.z + v.w * v.w;
#pragma unroll
  for (int off = 32; off; off >>= 1) ss += __shfl_xor(ss, off);
  __shared__ float red[4];
  if ((tid & 63) == 0) red[tid >> 6] = ss;
  __syncthreads();
  const float tot = red[0] + red[1] + red[2] + red[3];
  const float r = rsqrtf(tot * (1.0f / 1024.0f) + 1e-6f);
  float4 wv = *(const float4*)(w + tid * 4);
  u16x4 o;
  o.x = f2bf(v.x * r * wv.x); o.y = f2bf(v.y * r * wv.y);
  o.z = f2bf(v.z * r * wv.z); o.w = f2bf(v.w * r * wv.w);
  *(u16x4*)(h + (size_t)row * 1024 + tid * 4) = o;
}

// ---------------------------------------------------------------------------
// Sequential chaotic scan; now sums two split-K partials + folds b_in.
// ---------------------------------------------------------------------------
__device__ __forceinline__ void scan_load(const float* __restrict__ p0,
                                          const float* __restrict__ p1, int tb,
                                          float A2b, float (&buf)[8]) {
#pragma unroll
  for (int j = 0; j < 8; j++)
    buf[j] = fmaf(p0[(size_t)(tb + j) * 1024] + p1[(size_t)(tb + j) * 1024],
                  2.8853900817779268f, A2b);
}

__device__ __forceinline__ void scan_comp(float (&buf)[8], float m2A2, float& r,
                                          u16* __restrict__ o, int tb) {
#pragma unroll
  for (int j = 0; j < 8; j++) {
    float z = fmaf(m2A2, r, buf[j]);
    float e = __builtin_amdgcn_exp2f(z);
    r = __builtin_amdgcn_rcpf(1.0f + e);
    o[(size_t)(tb + j) * 1024] = f2bf(fmaf(-2.0f, r, 1.0f));
  }
}

__global__ __launch_bounds__(256) void scan_kernel(const float* __restrict__ pre,
                                                   const float* __restrict__ a_diag,
                                                   const float* __restrict__ b_in,
                                                   u16* __restrict__ hs) {
  const int T = 2048;
  const int idx = blockIdx.x * 256 + threadIdx.x;  // 0..2047
  const int b = idx >> 10, d = idx & 1023;
  const float* p0 = pre + (size_t)b * T * 1024 + d;
  const float* p1 = p0 + 4194304;  // second partial (M*D)
  u16* o = hs + (size_t)b * T * 1024 + d;
  const float A2 = a_diag[d] * 2.8853900817779268f;
  const float A2b = fmaf(2.8853900817779268f, b_in[d], A2);
  const float m2A2 = -2.0f * A2;
  float r = 0.5f;
  float b0[8], b1[8], b2[8], b3[8];
  scan_load(p0, p1, 0, A2b, b0); scan_load(p0, p1, 8, A2b, b1);
  scan_load(p0, p1, 16, A2b, b2); scan_load(p0, p1, 24, A2b, b3);
  for (int t0 = 0; t0 < T; t0 += 32) {
    scan_comp(b0, m2A2, r, o, t0);
    if (t0 + 32 < T) scan_load(p0, p1, t0 + 32, A2b, b0);
    scan_comp(b1, m2A2, r, o, t0 + 8);
    if (t0 + 32 < T) scan_load(p0, p1, t0 + 40, A2b, b1);
    scan_comp(b2, m2A2, r, o, t0 + 16);
    if (t0 + 32 < T) scan_load(p0, p1, t0 + 48, A2b, b2);
    scan_comp(b3, m2A2, r, o, t0 + 24);
    if (t0 + 32 < T) scan_load(p0, p1, t0 + 56, A2b, b3);
  }
}

// ---------------------------------------------------------------------------
// gemm128: NT bf16 GEMM, 128x128 tile, BK=64, 4 waves (2x2 of 64x64).
// Counted-vmcnt 2-phase dbuf: stage tile kt+1, vmcnt(8) (NOT 0) -> loads stay
// in flight across the MFMA phase; two raw barriers/iter. 64 FLOP/staged-byte
// (2x gemm64). Split-K via blockIdx.z (partials to Cf + z*Cstride).
// LDS swizzle: 128B row = 8 slots, slot ^= row&7; linear gload dest +
// inverse-swizzled global src (rule #21).
// EPI 0 = f32 store; EPI 2 = bf16 silu(v+bias)
// ---------------------------------------------------------------------------
template <int EPI>
__global__ __launch_bounds__(256) void gemm128(
    const u16* __restrict__ A, int lda, const u16* __restrict__ Bw, int ldb,
    const float* __restrict__ bias, float* Cf, u16* __restrict__ Cb, int ldc,
    int Kz, long long Cstride) {
  __shared__ char lds[65536];  // [buf][A 16K | B 16K] x2
  const int tid = threadIdx.x;
  const int lane = tid & 63;
  const int wid = tid >> 6;
  const int wm = wid >> 1, wn = wid & 1;
  const int tm = blockIdx.y * 128, tn = blockIdx.x * 128;
  A += (size_t)blockIdx.z * Kz;
  Bw += (size_t)blockIdx.z * Kz;
  Cf += (size_t)blockIdx.z * Cstride;

  // staging addresses (pass p: rows p*32 + tid>>3)
  const int srow = tid >> 3;
  const int sxor = ((tid & 7) ^ (srow & 7)) << 4;
  const char* pA = (const char*)A + (size_t)(tm + srow) * lda * 2 + sxor;
  const char* pB = (const char*)Bw + (size_t)(tn + srow) * ldb * 2 + sxor;
  const size_t pstepA = (size_t)32 * lda * 2;
  const size_t pstepB = (size_t)32 * ldb * 2;

#define STG128(kt, bufo)                                             \
  {                                                                  \
    char* d = lds + (bufo) + tid * 16;                               \
    const size_t kb = (size_t)(kt) << 7;                             \
    gload16(pA + kb, d);                                             \
    gload16(pA + pstepA + kb, d + 4096);                             \
    gload16(pA + 2 * pstepA + kb, d + 8192);                         \
    gload16(pA + 3 * pstepA + kb, d + 12288);                        \
    gload16(pB + kb, d + 16384);                                     \
    gload16(pB + pstepB + kb, d + 20480);                            \
    gload16(pB + 2 * pstepB + kb, d + 24576);                        \
    gload16(pB + 3 * pstepB + kb, d + 28672);                        \
  }

  // fragment read offsets: row*128 + ((slot base ^ (row&7))<<4), ks flips bit6
  const int lr = lane & 15;
  const int sb0 = (((lane >> 4) ^ (lane & 7)) << 4);
  const int sb[2] = {sb0, sb0 ^ 64};
  const int aB0 = (wm * 64 + lr) * 128;
  const int bB0 = 16384 + (wn * 64 + lr) * 128;

  f32x4 acc[4][4] = {};
  const int nkt = Kz >> 6;

  STG128(0, 0);
  int cur = 0;
  for (int kt = 0; kt < nkt; ++kt) {
    const bool more = (kt + 1 < nkt);
    if (more) STG128(kt + 1, (cur ^ 1) * 32768);
    if (more) { asm volatile("s_waitcnt vmcnt(8)" ::: "memory"); }
    else      { asm volatile("s_waitcnt vmcnt(0)" ::: "memory"); }
    __builtin_amdgcn_s_barrier();
    const char* base = lds + cur * 32768;
    bf16x8 aF[4][2], bF[4][2];
#pragma unroll
    for (int m = 0; m < 4; m++)
#pragma unroll
      for (int ks = 0; ks < 2; ks++) {
        aF[m][ks] = *(const bf16x8*)(base + aB0 + m * 2048 + sb[ks]);
        bF[m][ks] = *(const bf16x8*)(base + bB0 + m * 2048 + sb[ks]);
      }
#pragma unroll
    for (int ks = 0; ks < 2; ks++)
#pragma unroll
      for (int m = 0; m < 4; m++)
#pragma unroll
        for (int n = 0; n < 4; n++)
          acc[m][n] = __builtin_amdgcn_mfma_f32_16x16x32_bf16(aF[m][ks], bF[n][ks],
                                                              acc[m][n], 0, 0, 0);
    __builtin_amdgcn_s_barrier();
    cur ^= 1;
  }
#undef STG128

  const int crow = tm + wm * 64 + ((lane >> 4) << 2);
  const int ccol = tn + wn * 64 + lr;
#pragma unroll
  for (int m = 0; m < 4; m++) {
#pragma unroll
    for (int n = 0; n < 4; n++) {
      const int cg = ccol + n * 16;
      float bb = 0.0f;
      if (EPI == 2) bb = bias[cg];
#pragma unroll
      for (int j = 0; j < 4; j++) {
        const size_t off = (size_t)(crow + m * 16 + j) * ldc + cg;
        const float v = acc[m][n][j] + bb;
        if (EPI == 0) {
          Cf[off] = v;
        } else {
          const float sg = __builtin_amdgcn_rcpf(
              1.0f + __builtin_amdgcn_exp2f(-1.4426950408889634f * v));
          Cb[off] = f2bf(v * sg);
        }
      }
    }
  }
}

// ---------------------------------------------------------------------------
// gemm_lm8: 256x256 / BK=64 / 8 waves (2x4) / 8-phase counted-vmcnt schedule
// (T2+T3+T4+T5). K=1024 fixed (16 K-tiles, 8 iters x 2 tiles). LDS 128KB:
// buf{0,1} x regions [A0|A1|B0|B1] of 16KB (128 rows x 64k bf16).
// Quadrant order per tile: (mq,nq) = (0,0),(0,1),(1,0),(1,1); A ds_read at
// ph0/ph2, B at ph0/ph1 -> regions stage-safe one phase after last read.
// Stage slots: ph0:buf1.A0(t2i+1) ph1:buf1.A1 ph2:buf0.B0(t2i+2) ph3:buf0.B1
// ph4:buf0.A0 ph5:buf0.A1 ph6:buf1.B0(t2i+3) ph7:buf1.B1.
// vmcnt(4) before ph3/ph7 end-barriers (guide T4: never drain to 0 mid-loop).
// Grid: bid&7=XCD owns 2 row-tiles; 16 consecutive bids share one B col-tile
// window (B streams ~once via L3; per-XCD A slice 1MB in L2).
// ---------------------------------------------------------------------------
__global__ __launch_bounds__(512, 2) void gemm_lm8(
    const u16* __restrict__ A, const u16* __restrict__ Bw,
    float* __restrict__ C, int Nreal) {
  __shared__ char lds[131072];
  const int tid = threadIdx.x;
  const int lane = tid & 63;
  const int wid = tid >> 6;  // 0..7
  const int wr = wid >> 2;   // 0..1 (row half)
  const int wc = wid & 3;    // 0..3 (col quarter)
  const int bid = blockIdx.x;
  const int tm = (((bid & 7) << 1) + ((bid >> 3) & 1)) << 8;
  const int tn = (bid >> 4) << 8;

  // staging (per half-tile: 2 passes of 512x16B; rows 0..63 then 64..127)
  const int srow = tid >> 3;
  const int sxor = ((tid & 7) ^ (srow & 7)) << 4;
  const char* pAs = (const char*)A + ((size_t)(tm + srow) << 11) + sxor;
  const char* pBs = (const char*)Bw + ((size_t)(tn + srow) << 11) + sxor;

#define STG(p, h, kt, ro)                                      \
  {                                                            \
    char* d = lds + (ro) + tid * 16;                           \
    const char* s = (p) + ((size_t)(h) << 18) + ((kt) << 7);   \
    gload16(s, d);                                             \
    gload16(s + (64ull << 11), d + 8192);                      \
  }

  // fragment read bases (slot ^= row&7; row&7 == lane&7 everywhere)
  const int lr = lane & 15;
  const int sb0 = (((lane >> 4) ^ (lane & 7)) << 4);
  const int sb[2] = {sb0, sb0 ^ 64};
  const int aB = wr * 16384 + lr * 128;                          // + buf + mq*8192 + m*2048
  const int bB = 32768 + (wc >> 1) * 16384 + ((wc & 1) * 64 + lr) * 128;  // + nq*4096 + n*2048

  bf16x8 aR[4][2], bR[2][2][2];
  f32x4 acc[8][4] = {};

#define LDA_Q(bufo, mq)                                                         \
  _Pragma("unroll") for (int m_ = 0; m_ < 4; m_++)                              \
  _Pragma("unroll") for (int k_ = 0; k_ < 2; k_++)                              \
      aR[m_][k_] = *(const bf16x8*)(lds + (bufo) + aB + (mq)*8192 + m_*2048 + sb[k_]);

#define LDB_Q(bufo, nq)                                                         \
  _Pragma("unroll") for (int n_ = 0; n_ < 2; n_++)                              \
  _Pragma("unroll") for (int k_ = 0; k_ < 2; k_++)                              \
      bR[nq][n_][k_] = *(const bf16x8*)(lds + (bufo) + bB + (nq)*4096 + n_*2048 + sb[k_]);

#define MFMA_Q(mq, nq)                                                          \
  __builtin_amdgcn_s_setprio(1);                                                \
  _Pragma("unroll") for (int m_ = 0; m_ < 4; m_++)                              \
  _Pragma("unroll") for (int n_ = 0; n_ < 2; n_++)                              \
  _Pragma("unroll") for (int k_ = 0; k_ < 2; k_++)                              \
      acc[(mq)*4 + m_][(nq)*2 + n_] = __builtin_amdgcn_mfma_f32_16x16x32_bf16(  \
          aR[m_][k_], bR[nq][n_][k_], acc[(mq)*4 + m_][(nq)*2 + n_], 0, 0, 0);  \
  __builtin_amdgcn_s_setprio(0);

#define BAR() __builtin_amdgcn_s_barrier()
#define LGKM0() asm volatile("s_waitcnt lgkmcnt(0)" ::: "memory")

  // prologue: buf0 <- tile0 (all 4 regions); buf1 <- tile1 (B0,B1)
  STG(pAs, 0, 0, 0);
  STG(pAs, 1, 0, 16384);
  STG(pBs, 0, 0, 32768);
  STG(pBs, 1, 0, 49152);
  STG(pBs, 0, 1, 65536 + 32768);
  STG(pBs, 1, 1, 65536 + 49152);
  asm volatile("s_waitcnt vmcnt(4)" ::: "memory");
  BAR();

  for (int it = 0; it < 8; ++it) {
    const int t1 = 2 * it + 1, t2 = 2 * it + 2, t3 = 2 * it + 3;
    const bool st = (it < 7);
    // ph0: buf0 q(0,0)
    LDA_Q(0, 0); LDB_Q(0, 0);
    STG(pAs, 0, t1, 65536);
    BAR(); LGKM0(); MFMA_Q(0, 0); BAR();
    // ph1: buf0 q(0,1)
    LDB_Q(0, 1);
    STG(pAs, 1, t1, 65536 + 16384);
    BAR(); LGKM0(); MFMA_Q(0, 1); BAR();
    // ph2: buf0 q(1,0)
    LDA_Q(0, 1);
    if (st) STG(pBs, 0, t2, 32768);
    BAR(); LGKM0(); MFMA_Q(1, 0); BAR();
    // ph3: buf0 q(1,1)
    if (st) STG(pBs, 1, t2, 49152);
    BAR(); LGKM0(); MFMA_Q(1, 1);
    if (st) { asm volatile("s_waitcnt vmcnt(4)" ::: "memory"); }
    else    { asm volatile("s_waitcnt vmcnt(0)" ::: "memory"); }
    BAR();
    // ph4: buf1 q(0,0)
    LDA_Q(65536, 0); LDB_Q(65536, 0);
    if (st) STG(pAs, 0, t2, 0);
    BAR(); LGKM0(); MFMA_Q(0, 0); BAR();
    // ph5: buf1 q(0,1)
    LDB_Q(65536, 1);
    if (st) STG(pAs, 1, t2, 16384);
    BAR(); LGKM0(); MFMA_Q(0, 1); BAR();
    // ph6: buf1 q(1,0)
    LDA_Q(65536, 1);
    if (st) STG(pBs, 0, t3, 65536 + 32768);
    BAR(); LGKM0(); MFMA_Q(1, 0); BAR();
    // ph7: buf1 q(1,1)
    if (st) STG(pBs, 1, t3, 65536 + 49152);
    BAR(); LGKM0(); MFMA_Q(1, 1);
    if (st) { asm volatile("s_waitcnt vmcnt(4)" ::: "memory"); }
    else    { asm volatile("s_waitcnt vmcnt(0)" ::: "memory"); }
    BAR();
  }
#undef STG
#undef LDA_Q
#undef LDB_Q
#undef MFMA_Q
#undef BAR
#undef LGKM0

  // epilogue: row = tm + wr*128 + (M>>2)*64 + (M&3)*16 + (lane>>4)*4 + j
  //           col = tn + wc*64 + (N>>1)*32 + (N&1)*16 + (lane&15)
  const int crow = tm + wr * 128 + ((lane >> 4) << 2);
  const int ccol = tn + wc * 64 + lr;
#pragma unroll
  for (int M_ = 0; M_ < 8; M_++) {
    const int r = crow + (M_ >> 2) * 64 + (M_ & 3) * 16;
#pragma unroll
    for (int N_ = 0; N_ < 4; N_++) {
      const int cg = ccol + (N_ >> 1) * 32 + (N_ & 1) * 16;
      if (cg < Nreal) {
#pragma unroll
        for (int j = 0; j < 4; j++)
          C[(size_t)(r + j) * Nreal + cg] = acc[M_][N_][j];
      }
    }
  }
}

// ---------------------------------------------------------------------------
// Host
// ---------------------------------------------------------------------------
extern "C" void kernel_launch(void* const* d_in, const int* in_sizes, int n_in,
                              void* d_out, int out_size, void* d_ws, size_t ws_size,
                              hipStream_t stream) {
  const int T = 2048, D = 1024, V = 50257, L = 8;
  const int M = 2 * T;        // 4096
  const int Vpad = 50432;     // 197 * 256
  const size_t MD = (size_t)M * D;

  const int* ids = (const int*)d_in[0];
  const float* embed = (const float*)d_in[1];
  const float* norm1_w = (const float*)d_in[2];
  const float* norm2_w = (const float*)d_in[3];
  const float* a_diag = (const float*)d_in[4];
  const float* W_in = (const float*)d_in[5];
  const float* b_in = (const float*)d_in[6];
  const float* W_out = (const float*)d_in[7];
  const float* ff_w1 = (const float*)d_in[8];
  const float* ff_b1 = (const float*)d_in[9];
  const float* ff_w2 = (const float*)d_in[10];
  const float* ff_b2 = (const float*)d_in[11];
  const float* final_norm_w = (const float*)d_in[12];
  const float* lm_head_w = (const float*)d_in[13];

  // workspace
  char* w = (char*)d_ws;
  float* x = (float*)w;    w += MD * 4;            // f32 residual
  u16* h = (u16*)w;        w += MD * 2;            // bf16 norm out
  u16* hs = (u16*)w;       w += MD * 2;            // bf16 scan out
  u16* hff = (u16*)w;      w += MD * 2 * 2;        // bf16 FF mid (M x 2D)
  float* P = (float*)w;    w += MD * 4 * 2;        // partials: GEMM1 pre / FF2 (aliased)
  float* xP = (float*)w;   w += MD * 4 * 2;        // partials: GEMM2
  u16* WinT = (u16*)w;     w += (size_t)L * D * D * 2;
  u16* WoutT = (u16*)w;    w += (size_t)L * D * D * 2;
  u16* ffw1T = (u16*)w;    w += (size_t)L * 2 * D * D * 2;
  u16* ffw2T = (u16*)w;    w += (size_t)L * 2 * D * D * 2;
  u16* lmpad = (u16*)w;    w += (size_t)Vpad * D * 2;

  // weight prep
  lm_cast_kernel<<<Vpad, 256, 0, stream>>>(lm_head_w, lmpad);
  transpose_cast_kernel<<<dim3(32, 32, L), dim3(32, 8), 0, stream>>>(W_in, WinT, D, D);
  transpose_cast_kernel<<<dim3(64, 32, L), dim3(32, 8), 0, stream>>>(ff_w1, ffw1T, D, 2 * D);
  transpose_cast_kernel<<<dim3(32, 32, L), dim3(32, 8), 0, stream>>>(W_out, WoutT, D, D);
  transpose_cast_kernel<<<dim3(32, 64, L), dim3(32, 8), 0, stream>>>(ff_w2, ffw2T, 2 * D, D);

  embed_kernel<<<M, 256, 0, stream>>>(ids, embed, x);

  for (int l = 0; l < L; l++) {
    // norm1: x += FF2 partials(prev layer) + b2(prev); h = rms(x)*w1
    if (l == 0)
      norm_fused<<<M, 256, 0, stream>>>(x, nullptr, nullptr, norm1_w, nullptr, h);
    else
      norm_fused<<<M, 256, 0, stream>>>(x, P, ff_b2 + (size_t)(l - 1) * D,
                                        norm1_w + (size_t)l * D, x, h);
    // GEMM1 (split-K=2): h @ WinT -> P (pre partials)
    gemm128<0><<<dim3(8, 32, 2), 256, 0, stream>>>(
        h, D, WinT + (size_t)l * D * D, D, nullptr, P, nullptr, D, 512, (long long)MD);
    // scan: reads P0+P1, folds b_in
    scan_kernel<<<8, 256, 0, stream>>>(P, a_diag + (size_t)l * D,
                                       b_in + (size_t)l * D, hs);
    // GEMM2 (split-K=2): hs @ WoutT -> xP
    gemm128<0><<<dim3(8, 32, 2), 256, 0, stream>>>(
        hs, D, WoutT + (size_t)l * D * D, D, nullptr, xP, nullptr, D, 512, (long long)MD);
    // norm2: x += xP0+xP1; h = rms(x)*w2
    norm_fused<<<M, 256, 0, stream>>>(x, xP, nullptr, norm2_w + (size_t)l * D, x, h);
    // FF1: h @ ffw1T -> silu -> hff (bf16), full K
    gemm128<2><<<dim3(16, 32, 1), 256, 0, stream>>>(
        h, D, ffw1T + (size_t)l * 2 * D * D, D, ff_b1 + (size_t)l * 2 * D,
        nullptr, hff, 2 * D, 1024, 0);
    // FF2 (split-K=2, K=2048): hff @ ffw2T -> P (residual partials for next norm1)
    gemm128<0><<<dim3(8, 32, 2), 256, 0, stream>>>(
        hff, 2 * D, ffw2T + (size_t)l * 2 * D * D, 2 * D, nullptr, P, nullptr, D,
        1024, (long long)MD);
  }

  // final norm: x += FF2 partials + b2[7]; h = rms(x)*w
  norm_fused<<<M, 256, 0, stream>>>(x, P, ff_b2 + (size_t)(L - 1) * D,
                                    final_norm_w, nullptr, h);
  // lm head: 256^2 8-phase
  gemm_lm8<<<dim3(8 * 394), 512, 0, stream>>>(h, lmpad, (float*)d_out, V);
}